// Round 1
// baseline (3535.297 us; speedup 1.0000x reference)
//
#include <hip/hip_runtime.h>

#define N_NODES 100000
#define N_EDGES 3200000
#define HDIM 16

// ---- monotonic float<->uint mapping so unsigned atomicMax == float max ----
__device__ __forceinline__ unsigned f2u(float f) {
    unsigned u = __float_as_uint(f);
    return (u & 0x80000000u) ? ~u : (u | 0x80000000u);
}
__device__ __forceinline__ float u2f(unsigned u) {
    u = (u & 0x80000000u) ? (u & 0x7fffffffu) : ~u;
    return __uint_as_float(u);
}

// ---- init agg buffer to sentinel 0 (== below encode(-inf)) ----
__global__ void init_agg(unsigned* __restrict__ aggu, int n4) {
    int i = blockIdx.x * blockDim.x + threadIdx.x;
    if (i < n4) {
        ((uint4*)aggu)[i] = make_uint4(0u, 0u, 0u, 0u);
    }
}

// ---- edge scatter-max: 4 threads per edge, 4 features each ----
__global__ void edge_max(const float* __restrict__ h,
                         const int* __restrict__ src,
                         const int* __restrict__ dst,
                         unsigned* __restrict__ aggu) {
    int idx = blockIdx.x * blockDim.x + threadIdx.x;
    if (idx >= N_EDGES * 4) return;
    int e = idx >> 2;
    int g = idx & 3;
    int s = src[e];
    int d = dst[e];
    float4 v = ((const float4*)(h + (size_t)s * HDIM))[g];
    unsigned* o = aggu + (size_t)d * HDIM + g * 4;
    atomicMax(o + 0, f2u(v.x));
    atomicMax(o + 1, f2u(v.y));
    atomicMax(o + 2, f2u(v.z));
    atomicMax(o + 3, f2u(v.w));
}

// ---- per-node dense: out = agg@Wl + b + hin@Wr (+relu / +log_softmax) ----
template <int HOUT, bool RELU, bool LSM>
__global__ void node_dense(const float* __restrict__ hin,
                           const unsigned* __restrict__ aggu,
                           const float* __restrict__ Wl,
                           const float* __restrict__ Wr,
                           const float* __restrict__ b,
                           float* __restrict__ hout) {
    __shared__ float sWl[HDIM * HOUT];
    __shared__ float sWr[HDIM * HOUT];
    __shared__ float sb[HOUT];
    int t = threadIdx.x;
    if (t < HDIM * HOUT) {
        sWl[t] = Wl[t];
        sWr[t] = Wr[t];
    }
    if (t < HOUT) sb[t] = b[t];
    __syncthreads();

    int i = blockIdx.x * blockDim.x + t;
    if (i >= N_NODES) return;

    float a[HDIM], x[HDIM];
    const uint4* ap = (const uint4*)(aggu + (size_t)i * HDIM);
    const float4* xp = (const float4*)(hin + (size_t)i * HDIM);
#pragma unroll
    for (int q = 0; q < 4; ++q) {
        uint4 au = ap[q];
        a[q * 4 + 0] = au.x ? u2f(au.x) : 0.0f;
        a[q * 4 + 1] = au.y ? u2f(au.y) : 0.0f;
        a[q * 4 + 2] = au.z ? u2f(au.z) : 0.0f;
        a[q * 4 + 3] = au.w ? u2f(au.w) : 0.0f;
        float4 xv = xp[q];
        x[q * 4 + 0] = xv.x;
        x[q * 4 + 1] = xv.y;
        x[q * 4 + 2] = xv.z;
        x[q * 4 + 3] = xv.w;
    }

    float o[HOUT];
#pragma unroll
    for (int ho = 0; ho < HOUT; ++ho) o[ho] = sb[ho];
#pragma unroll
    for (int f = 0; f < HDIM; ++f) {
        float av = a[f], xv = x[f];
#pragma unroll
        for (int ho = 0; ho < HOUT; ++ho) {
            o[ho] += av * sWl[f * HOUT + ho] + xv * sWr[f * HOUT + ho];
        }
    }

    if (RELU) {
#pragma unroll
        for (int ho = 0; ho < HOUT; ++ho) o[ho] = fmaxf(o[ho], 0.0f);
    }
    if (LSM) {
        // HOUT == 2 here
        float m = fmaxf(o[0], o[1]);
        float lse = m + logf(expf(o[0] - m) + expf(o[1] - m));
#pragma unroll
        for (int ho = 0; ho < HOUT; ++ho) o[ho] -= lse;
    }

    float* op = hout + (size_t)i * HOUT;
#pragma unroll
    for (int ho = 0; ho < HOUT; ++ho) op[ho] = o[ho];
}

extern "C" void kernel_launch(void* const* d_in, const int* in_sizes, int n_in,
                              void* d_out, int out_size, void* d_ws, size_t ws_size,
                              hipStream_t stream) {
    const float* x      = (const float*)d_in[0];
    const int*   ei     = (const int*)d_in[1];
    const float* Wl1    = (const float*)d_in[2];
    const float* Wr1    = (const float*)d_in[3];
    const float* b1     = (const float*)d_in[4];
    const float* Wl_mid = (const float*)d_in[5];
    const float* Wr_mid = (const float*)d_in[6];
    const float* b_mid  = (const float*)d_in[7];
    const float* Wl7    = (const float*)d_in[8];
    const float* Wr7    = (const float*)d_in[9];
    const float* b7     = (const float*)d_in[10];
    float* out = (float*)d_out;

    const int* src = ei;
    const int* dst = ei + N_EDGES;

    char* ws = (char*)d_ws;
    const size_t hbytes = (size_t)N_NODES * HDIM * sizeof(float);
    unsigned* aggu = (unsigned*)ws;
    float* hA = (float*)(ws + hbytes);
    float* hB = (float*)(ws + 2 * hbytes);

    const int n4 = N_NODES * HDIM / 4;
    dim3 bInit((n4 + 255) / 256);
    dim3 bEdge((N_EDGES * 4 + 255) / 256);
    dim3 bNode((N_NODES + 255) / 256);

    // ---- layer 1: x(16) -> hA(16), relu ----
    init_agg<<<bInit, 256, 0, stream>>>(aggu, n4);
    edge_max<<<bEdge, 256, 0, stream>>>(x, src, dst, aggu);
    node_dense<16, true, false><<<bNode, 256, 0, stream>>>(x, aggu, Wl1, Wr1, b1, hA);

    // ---- layers 2..6 ----
    float* cur = hA;
    float* nxt = hB;
    for (int i = 0; i < 5; ++i) {
        init_agg<<<bInit, 256, 0, stream>>>(aggu, n4);
        edge_max<<<bEdge, 256, 0, stream>>>(cur, src, dst, aggu);
        node_dense<16, true, false><<<bNode, 256, 0, stream>>>(
            cur, aggu, Wl_mid + i * 256, Wr_mid + i * 256, b_mid + i * 16, nxt);
        float* tmp = cur; cur = nxt; nxt = tmp;
    }

    // ---- layer 7: 16 -> 2, log_softmax ----
    init_agg<<<bInit, 256, 0, stream>>>(aggu, n4);
    edge_max<<<bEdge, 256, 0, stream>>>(cur, src, dst, aggu);
    node_dense<2, false, true><<<bNode, 256, 0, stream>>>(cur, aggu, Wl7, Wr7, b7, out);
}

// Round 2
// 779.672 us; speedup vs baseline: 4.5343x; 4.5343x over previous
//
#include <hip/hip_runtime.h>
#include <float.h>

#define N_NODES 100000
#define N_EDGES 3200000
#define HDIM 16
#define SCAN_B 512
#define NBLK ((N_NODES + SCAN_B - 1) / SCAN_B)   // 196

// ---------------- CSR build ----------------

__global__ void zero_ints(int* __restrict__ p, int n) {
    int i = blockIdx.x * blockDim.x + threadIdx.x;
    if (i < n) p[i] = 0;
}

__global__ void hist_deg(const int* __restrict__ dst, int* __restrict__ deg) {
    int e = blockIdx.x * blockDim.x + threadIdx.x;
    if (e < N_EDGES) atomicAdd(&deg[dst[e]], 1);
}

// per-block exclusive scan; block sums out
__global__ void scan_block(const int* __restrict__ deg, int* __restrict__ row_ptr,
                           int* __restrict__ bsum) {
    __shared__ int s[SCAN_B];
    int t = threadIdx.x;
    int i = blockIdx.x * SCAN_B + t;
    int v = (i < N_NODES) ? deg[i] : 0;
    s[t] = v;
    __syncthreads();
#pragma unroll
    for (int off = 1; off < SCAN_B; off <<= 1) {
        int u = (t >= off) ? s[t - off] : 0;
        __syncthreads();
        s[t] += u;
        __syncthreads();
    }
    if (i < N_NODES) row_ptr[i] = s[t] - v;      // exclusive within block
    if (t == SCAN_B - 1) bsum[blockIdx.x] = s[t];
}

// single-block scan of block sums -> exclusive offsets
__global__ void scan_bsums(int* __restrict__ bsum, int nb) {
    __shared__ int s[SCAN_B];
    int t = threadIdx.x;
    int v = (t < nb) ? bsum[t] : 0;
    s[t] = v;
    __syncthreads();
#pragma unroll
    for (int off = 1; off < SCAN_B; off <<= 1) {
        int u = (t >= off) ? s[t - off] : 0;
        __syncthreads();
        s[t] += u;
        __syncthreads();
    }
    if (t < nb) bsum[t] = s[t] - v;              // exclusive
}

__global__ void add_offsets(int* __restrict__ row_ptr, const int* __restrict__ bsum,
                            int* __restrict__ cursor) {
    int i = blockIdx.x * blockDim.x + threadIdx.x;
    if (i < N_NODES) {
        int v = row_ptr[i] + bsum[i / SCAN_B];
        row_ptr[i] = v;
        cursor[i] = v;
    }
    if (i == 0) row_ptr[N_NODES] = N_EDGES;
}

__global__ void scatter_edges(const int* __restrict__ src, const int* __restrict__ dst,
                              int* __restrict__ cursor, int* __restrict__ col) {
    int e = blockIdx.x * blockDim.x + threadIdx.x;
    if (e < N_EDGES) {
        int p = atomicAdd(&cursor[dst[e]], 1);
        col[p] = src[e];
    }
}

// ---------------- fused SAGE layer: agg = max_j h[col[j]]; out = agg@Wl + b + h@Wr ----------------
// 256 threads/block = 64 nodes x 4 threads; each thread owns a float4 feature slice.

template <int HOUT, bool RELU, bool LSM>
__global__ void sage_layer(const float* __restrict__ h,
                           const int* __restrict__ row_ptr,
                           const int* __restrict__ col,
                           const float* __restrict__ Wl,
                           const float* __restrict__ Wr,
                           const float* __restrict__ b,
                           float* __restrict__ out) {
    __shared__ float sWl[HDIM * HOUT];
    __shared__ float sWr[HDIM * HOUT];
    __shared__ float sb[HOUT];
    __shared__ float sagg[64][HDIM + 1];
    __shared__ float sx[64][HDIM + 1];

    int t = threadIdx.x;
    if (t < HDIM * HOUT) { sWl[t] = Wl[t]; sWr[t] = Wr[t]; }
    if (t < HOUT) sb[t] = b[t];

    int nl = t >> 2;                 // local node 0..63
    int g  = t & 3;                  // feature quad 0..3
    int i  = blockIdx.x * 64 + nl;

    float4 acc = make_float4(-FLT_MAX, -FLT_MAX, -FLT_MAX, -FLT_MAX);
    if (i < N_NODES) {
        int beg = row_ptr[i];
        int end = row_ptr[i + 1];
        for (int j = beg; j < end; ++j) {
            int nb = col[j];
            float4 v = ((const float4*)h)[nb * 4 + g];
            acc.x = fmaxf(acc.x, v.x);
            acc.y = fmaxf(acc.y, v.y);
            acc.z = fmaxf(acc.z, v.z);
            acc.w = fmaxf(acc.w, v.w);
        }
        if (beg == end) acc = make_float4(0.f, 0.f, 0.f, 0.f);  // isolated node
        float4 xv = ((const float4*)h)[i * 4 + g];
        sagg[nl][g * 4 + 0] = acc.x;
        sagg[nl][g * 4 + 1] = acc.y;
        sagg[nl][g * 4 + 2] = acc.z;
        sagg[nl][g * 4 + 3] = acc.w;
        sx[nl][g * 4 + 0] = xv.x;
        sx[nl][g * 4 + 1] = xv.y;
        sx[nl][g * 4 + 2] = xv.z;
        sx[nl][g * 4 + 3] = xv.w;
    }
    __syncthreads();

    if (i < N_NODES) {
        if (HOUT == 16) {
            float o[4];
#pragma unroll
            for (int c = 0; c < 4; ++c) o[c] = sb[g * 4 + c];
#pragma unroll
            for (int f = 0; f < HDIM; ++f) {
                float a  = sagg[nl][f];
                float xv = sx[nl][f];
#pragma unroll
                for (int c = 0; c < 4; ++c) {
                    o[c] += a * sWl[f * HOUT + g * 4 + c] + xv * sWr[f * HOUT + g * 4 + c];
                }
            }
            if (RELU) {
#pragma unroll
                for (int c = 0; c < 4; ++c) o[c] = fmaxf(o[c], 0.f);
            }
            float4 ov = make_float4(o[0], o[1], o[2], o[3]);
            ((float4*)out)[i * 4 + g] = ov;
        } else {  // HOUT == 2, final layer with log_softmax
            if (g == 0) {
                float o0 = sb[0], o1 = sb[1];
#pragma unroll
                for (int f = 0; f < HDIM; ++f) {
                    float a  = sagg[nl][f];
                    float xv = sx[nl][f];
                    o0 += a * sWl[f * 2 + 0] + xv * sWr[f * 2 + 0];
                    o1 += a * sWl[f * 2 + 1] + xv * sWr[f * 2 + 1];
                }
                if (LSM) {
                    float m = fmaxf(o0, o1);
                    float lse = m + logf(expf(o0 - m) + expf(o1 - m));
                    o0 -= lse;
                    o1 -= lse;
                }
                out[i * 2 + 0] = o0;
                out[i * 2 + 1] = o1;
            }
        }
    }
}

// ---------------- launch ----------------

extern "C" void kernel_launch(void* const* d_in, const int* in_sizes, int n_in,
                              void* d_out, int out_size, void* d_ws, size_t ws_size,
                              hipStream_t stream) {
    const float* x      = (const float*)d_in[0];
    const int*   ei     = (const int*)d_in[1];
    const float* Wl1    = (const float*)d_in[2];
    const float* Wr1    = (const float*)d_in[3];
    const float* b1     = (const float*)d_in[4];
    const float* Wl_mid = (const float*)d_in[5];
    const float* Wr_mid = (const float*)d_in[6];
    const float* b_mid  = (const float*)d_in[7];
    const float* Wl7    = (const float*)d_in[8];
    const float* Wr7    = (const float*)d_in[9];
    const float* b7     = (const float*)d_in[10];
    float* out = (float*)d_out;

    const int* src = ei;
    const int* dst = ei + N_EDGES;

    // workspace layout (all 256B-aligned)
    char* ws = (char*)d_ws;
    size_t off = 0;
    auto alloc = [&](size_t bytes) {
        void* p = ws + off;
        off += (bytes + 255) & ~(size_t)255;
        return p;
    };
    int*   col     = (int*)alloc((size_t)N_EDGES * 4);
    int*   row_ptr = (int*)alloc((size_t)(N_NODES + 1) * 4);
    int*   cursor  = (int*)alloc((size_t)N_NODES * 4);   // also deg
    int*   bsum    = (int*)alloc((size_t)SCAN_B * 4);
    float* hA      = (float*)alloc((size_t)N_NODES * HDIM * 4);
    float* hB      = (float*)alloc((size_t)N_NODES * HDIM * 4);

    int* deg = cursor;  // reuse: deg consumed by scan before cursor is written

    dim3 bN((N_NODES + 255) / 256);
    dim3 bE((N_EDGES + 255) / 256);
    dim3 bL((N_NODES + 63) / 64);

    // ---- build CSR (counting sort by dst) ----
    zero_ints<<<bN, 256, 0, stream>>>(deg, N_NODES);
    hist_deg<<<bE, 256, 0, stream>>>(dst, deg);
    scan_block<<<NBLK, SCAN_B, 0, stream>>>(deg, row_ptr, bsum);
    scan_bsums<<<1, SCAN_B, 0, stream>>>(bsum, NBLK);
    add_offsets<<<bN, 256, 0, stream>>>(row_ptr, bsum, cursor);
    scatter_edges<<<bE, 256, 0, stream>>>(src, dst, cursor, col);

    // ---- 7 fused layers ----
    sage_layer<16, true, false><<<bL, 256, 0, stream>>>(x, row_ptr, col, Wl1, Wr1, b1, hA);

    float* cur = hA;
    float* nxt = hB;
    for (int i = 0; i < 5; ++i) {
        sage_layer<16, true, false><<<bL, 256, 0, stream>>>(
            cur, row_ptr, col, Wl_mid + i * 256, Wr_mid + i * 256, b_mid + i * 16, nxt);
        float* tmp = cur; cur = nxt; nxt = tmp;
    }

    sage_layer<2, false, true><<<bL, 256, 0, stream>>>(cur, row_ptr, col, Wl7, Wr7, b7, out);
}

// Round 3
// 368.892 us; speedup vs baseline: 9.5836x; 2.1136x over previous
//
#include <hip/hip_runtime.h>
#include <float.h>

#define N_NODES 100000
#define N_EDGES 3200000
#define HDIM 16
#define NB 391                       // ceil(N_NODES/256) buckets of 256 nodes
#define PASS1_EPB 8192
#define PASS1_BLOCKS ((N_EDGES + PASS1_EPB - 1) / PASS1_EPB)   // 391
#define CAP 10240                    // LDS col staging capacity (mean bucket 8192, std ~90)

// ---------------- small utils ----------------

__global__ void zero_ints(int* __restrict__ p, int n) {
    int i = blockIdx.x * blockDim.x + threadIdx.x;
    if (i < n) p[i] = 0;
}

// ---------------- CSR build: bucketed counting sort ----------------

__global__ void bucket_hist(const int* __restrict__ dst, int* __restrict__ bcnt) {
    __shared__ int lh[NB];
    for (int i = threadIdx.x; i < NB; i += blockDim.x) lh[i] = 0;
    __syncthreads();
    int stride = gridDim.x * blockDim.x;
    for (int e = blockIdx.x * blockDim.x + threadIdx.x; e < N_EDGES; e += stride)
        atomicAdd(&lh[dst[e] >> 8], 1);
    __syncthreads();
    for (int i = threadIdx.x; i < NB; i += blockDim.x)
        if (lh[i]) atomicAdd(&bcnt[i], lh[i]);
}

// single block: exclusive scan bcnt -> bbase[0..NB], init bcursor, row_ptr[N]=E
__global__ void bucket_scan(const int* __restrict__ bcnt, int* __restrict__ bbase,
                            int* __restrict__ bcursor, int* __restrict__ row_ptr) {
    __shared__ int s[512];
    int t = threadIdx.x;
    int v = (t < NB) ? bcnt[t] : 0;
    s[t] = v;
    __syncthreads();
    for (int off = 1; off < 512; off <<= 1) {
        int u = (t >= off) ? s[t - off] : 0;
        __syncthreads();
        s[t] += u;
        __syncthreads();
    }
    if (t < NB) { int ex = s[t] - v; bbase[t] = ex; bcursor[t] = ex; }
    if (t == 0) { bbase[NB] = N_EDGES; row_ptr[N_NODES] = N_EDGES; }
}

// block-aggregated append of packed (src | (d&255)<<17) into bucket regions
__global__ __launch_bounds__(1024)
void pass1_bucket(const int* __restrict__ src, const int* __restrict__ dst,
                  int* __restrict__ bcursor, unsigned* __restrict__ pairs) {
    __shared__ int lh[NB], lbase[NB], lcur[NB];
    int t = threadIdx.x;
    int e0 = blockIdx.x * PASS1_EPB;
    int n = min(PASS1_EPB, N_EDGES - e0);
    for (int i = t; i < NB; i += 1024) { lh[i] = 0; lcur[i] = 0; }
    __syncthreads();
    for (int j = t; j < n; j += 1024) atomicAdd(&lh[dst[e0 + j] >> 8], 1);
    __syncthreads();
    for (int i = t; i < NB; i += 1024) {
        int c = lh[i];
        lbase[i] = c ? atomicAdd(&bcursor[i], c) : 0;
    }
    __syncthreads();
    for (int j = t; j < n; j += 1024) {
        int e = e0 + j;
        int d = dst[e];
        int bk = d >> 8;
        int r = atomicAdd(&lcur[bk], 1);
        pairs[lbase[bk] + r] = (unsigned)src[e] | ((unsigned)(d & 255) << 17);
    }
}

// one block per bucket: LDS counting sort -> row_ptr + coalesced col
__global__ __launch_bounds__(1024)
void pass2_sort(const unsigned* __restrict__ pairs, const int* __restrict__ bbase,
                int* __restrict__ row_ptr, int* __restrict__ col) {
    __shared__ int sdeg[256], ssc[256], scur[256];
    __shared__ int colst[CAP];
    int t = threadIdx.x;
    int b = blockIdx.x;
    int base = bbase[b];
    int cnt = bbase[b + 1] - base;
    int node0 = b << 8;
    int nn = min(256, N_NODES - node0);
    if (t < 256) sdeg[t] = 0;
    __syncthreads();
    for (int j = t; j < cnt; j += 1024) atomicAdd(&sdeg[pairs[base + j] >> 17], 1);
    __syncthreads();
    if (t < 256) ssc[t] = sdeg[t];
    __syncthreads();
    for (int off = 1; off < 256; off <<= 1) {
        int u = 0;
        if (t < 256 && t >= off) u = ssc[t - off];
        __syncthreads();
        if (t < 256) ssc[t] += u;
        __syncthreads();
    }
    if (t < 256) {
        int ex = ssc[t] - sdeg[t];
        if (t < nn) row_ptr[node0 + t] = base + ex;
        scur[t] = ex;
    }
    __syncthreads();
    for (int j = t; j < cnt; j += 1024) {
        unsigned v = pairs[base + j];
        int dl = v >> 17;
        int s = v & 0x1FFFF;
        int p = atomicAdd(&scur[dl], 1);
        if (p < CAP) colst[p] = s;
        else col[base + p] = s;   // overflow slow path (statistically never)
    }
    __syncthreads();
    int lim = min(cnt, CAP);
    for (int j = t; j < lim; j += 1024) col[base + j] = colst[j];
}

// ---------------- fused SAGE layer ----------------
// 64 nodes x 4 threads per block; each thread max-reduces full rows over 1/4 of
// the neighbors, then a 2-round shfl_xor butterfly combines the 4 partials.

__device__ __forceinline__ float4 fmax4(float4 a, float4 b) {
    return make_float4(fmaxf(a.x, b.x), fmaxf(a.y, b.y), fmaxf(a.z, b.z), fmaxf(a.w, b.w));
}
__device__ __forceinline__ float4 shflx4(float4 a, int m) {
    return make_float4(__shfl_xor(a.x, m), __shfl_xor(a.y, m),
                       __shfl_xor(a.z, m), __shfl_xor(a.w, m));
}

template <int HOUT, bool RELU, bool LSM>
__global__ void sage_layer(const float* __restrict__ h,
                           const int* __restrict__ row_ptr,
                           const int* __restrict__ col,
                           const float* __restrict__ Wl,
                           const float* __restrict__ Wr,
                           const float* __restrict__ b,
                           float* __restrict__ out) {
    __shared__ float sWl[HDIM * HOUT];
    __shared__ float sWr[HDIM * HOUT];
    __shared__ float sb[HOUT];
    int t = threadIdx.x;
    if (t < HDIM * HOUT) { sWl[t] = Wl[t]; sWr[t] = Wr[t]; }
    if (t < HOUT) sb[t] = b[t];
    __syncthreads();

    int nl = t >> 2, g = t & 3;
    int i = blockIdx.x * 64 + nl;
    if (i >= N_NODES) return;

    int beg = row_ptr[i], end = row_ptr[i + 1];
    const float4* h4 = (const float4*)h;

    float4 a0, a1, a2, a3;
    a0 = a1 = a2 = a3 = make_float4(-FLT_MAX, -FLT_MAX, -FLT_MAX, -FLT_MAX);

    int j = beg + g;
    for (; j + 4 < end; j += 8) {
        int n0 = col[j], n1 = col[j + 4];
        float4 v0 = h4[n0 * 4 + 0], v1 = h4[n0 * 4 + 1];
        float4 v2 = h4[n0 * 4 + 2], v3 = h4[n0 * 4 + 3];
        float4 w0 = h4[n1 * 4 + 0], w1 = h4[n1 * 4 + 1];
        float4 w2 = h4[n1 * 4 + 2], w3 = h4[n1 * 4 + 3];
        a0 = fmax4(a0, fmax4(v0, w0));
        a1 = fmax4(a1, fmax4(v1, w1));
        a2 = fmax4(a2, fmax4(v2, w2));
        a3 = fmax4(a3, fmax4(v3, w3));
    }
    if (j < end) {
        int n0 = col[j];
        a0 = fmax4(a0, h4[n0 * 4 + 0]);
        a1 = fmax4(a1, h4[n0 * 4 + 1]);
        a2 = fmax4(a2, h4[n0 * 4 + 2]);
        a3 = fmax4(a3, h4[n0 * 4 + 3]);
    }
    // butterfly combine across the node's 4 lanes
    a0 = fmax4(a0, shflx4(a0, 1)); a1 = fmax4(a1, shflx4(a1, 1));
    a2 = fmax4(a2, shflx4(a2, 1)); a3 = fmax4(a3, shflx4(a3, 1));
    a0 = fmax4(a0, shflx4(a0, 2)); a1 = fmax4(a1, shflx4(a1, 2));
    a2 = fmax4(a2, shflx4(a2, 2)); a3 = fmax4(a3, shflx4(a3, 2));
    if (beg == end) {
        a0 = a1 = a2 = a3 = make_float4(0.f, 0.f, 0.f, 0.f);  // isolated node
    }

    float4 x0 = h4[i * 4 + 0], x1 = h4[i * 4 + 1];
    float4 x2 = h4[i * 4 + 2], x3 = h4[i * 4 + 3];

    float av[16] = {a0.x, a0.y, a0.z, a0.w, a1.x, a1.y, a1.z, a1.w,
                    a2.x, a2.y, a2.z, a2.w, a3.x, a3.y, a3.z, a3.w};
    float xv[16] = {x0.x, x0.y, x0.z, x0.w, x1.x, x1.y, x1.z, x1.w,
                    x2.x, x2.y, x2.z, x2.w, x3.x, x3.y, x3.z, x3.w};

    if (HOUT == 16) {
        float o[4];
#pragma unroll
        for (int c = 0; c < 4; ++c) o[c] = sb[g * 4 + c];
#pragma unroll
        for (int f = 0; f < 16; ++f) {
#pragma unroll
            for (int c = 0; c < 4; ++c)
                o[c] += av[f] * sWl[f * 16 + g * 4 + c] + xv[f] * sWr[f * 16 + g * 4 + c];
        }
        if (RELU) {
#pragma unroll
            for (int c = 0; c < 4; ++c) o[c] = fmaxf(o[c], 0.f);
        }
        ((float4*)out)[i * 4 + g] = make_float4(o[0], o[1], o[2], o[3]);
    } else {  // HOUT == 2 final layer
        if (g == 0) {
            float o0 = sb[0], o1 = sb[1];
#pragma unroll
            for (int f = 0; f < 16; ++f) {
                o0 += av[f] * sWl[f * 2 + 0] + xv[f] * sWr[f * 2 + 0];
                o1 += av[f] * sWl[f * 2 + 1] + xv[f] * sWr[f * 2 + 1];
            }
            if (LSM) {
                float m = fmaxf(o0, o1);
                float lse = m + logf(expf(o0 - m) + expf(o1 - m));
                o0 -= lse;
                o1 -= lse;
            }
            out[i * 2 + 0] = o0;
            out[i * 2 + 1] = o1;
        }
    }
}

// ---------------- launch ----------------

extern "C" void kernel_launch(void* const* d_in, const int* in_sizes, int n_in,
                              void* d_out, int out_size, void* d_ws, size_t ws_size,
                              hipStream_t stream) {
    const float* x      = (const float*)d_in[0];
    const int*   ei     = (const int*)d_in[1];
    const float* Wl1    = (const float*)d_in[2];
    const float* Wr1    = (const float*)d_in[3];
    const float* b1     = (const float*)d_in[4];
    const float* Wl_mid = (const float*)d_in[5];
    const float* Wr_mid = (const float*)d_in[6];
    const float* b_mid  = (const float*)d_in[7];
    const float* Wl7    = (const float*)d_in[8];
    const float* Wr7    = (const float*)d_in[9];
    const float* b7     = (const float*)d_in[10];
    float* out = (float*)d_out;

    const int* src = ei;
    const int* dst = ei + N_EDGES;

    char* ws = (char*)d_ws;
    size_t off = 0;
    auto alloc = [&](size_t bytes) {
        void* p = ws + off;
        off += (bytes + 255) & ~(size_t)255;
        return p;
    };
    unsigned* pairs  = (unsigned*)alloc((size_t)N_EDGES * 4);
    int*     col     = (int*)alloc((size_t)N_EDGES * 4);
    int*     row_ptr = (int*)alloc((size_t)(N_NODES + 1) * 4);
    int*     bcnt    = (int*)alloc((size_t)NB * 4);
    int*     bbase   = (int*)alloc((size_t)(NB + 1) * 4);
    int*     bcursor = (int*)alloc((size_t)NB * 4);
    float*   hA      = (float*)alloc((size_t)N_NODES * HDIM * 4);
    float*   hB      = (float*)alloc((size_t)N_NODES * HDIM * 4);

    dim3 bL((N_NODES + 63) / 64);

    // ---- CSR build ----
    zero_ints<<<(NB + 255) / 256, 256, 0, stream>>>(bcnt, NB);
    bucket_hist<<<512, 256, 0, stream>>>(dst, bcnt);
    bucket_scan<<<1, 512, 0, stream>>>(bcnt, bbase, bcursor, row_ptr);
    pass1_bucket<<<PASS1_BLOCKS, 1024, 0, stream>>>(src, dst, bcursor, pairs);
    pass2_sort<<<NB, 1024, 0, stream>>>(pairs, bbase, row_ptr, col);

    // ---- 7 fused layers ----
    sage_layer<16, true, false><<<bL, 256, 0, stream>>>(x, row_ptr, col, Wl1, Wr1, b1, hA);

    float* cur = hA;
    float* nxt = hB;
    for (int i = 0; i < 5; ++i) {
        sage_layer<16, true, false><<<bL, 256, 0, stream>>>(
            cur, row_ptr, col, Wl_mid + i * 256, Wr_mid + i * 256, b_mid + i * 16, nxt);
        float* tmp = cur; cur = nxt; nxt = tmp;
    }

    sage_layer<2, false, true><<<bL, 256, 0, stream>>>(cur, row_ptr, col, Wl7, Wr7, b7, out);
}

// Round 4
// 270.000 us; speedup vs baseline: 13.0937x; 1.3663x over previous
//
#include <hip/hip_runtime.h>
#include <hip/hip_fp16.h>
#include <float.h>

#define N_NODES 100000
#define N_EDGES 3200000
#define HDIM 16
#define NB 391                       // ceil(N_NODES/256) buckets of 256 nodes
#define PASS1_EPB 8192
#define PASS1_BLOCKS ((N_EDGES + PASS1_EPB - 1) / PASS1_EPB)   // 391
#define CAP 10240                    // LDS col staging (bucket mean 8192, sigma ~90)

typedef unsigned u32;

__device__ __forceinline__ u32 pkmax(u32 a, u32 b) {
    u32 r;
    asm("v_pk_max_f16 %0, %1, %2" : "=v"(r) : "v"(a), "v"(b));
    return r;
}
__device__ __forceinline__ float2 h2f2(u32 u) {
    __half2 h = *reinterpret_cast<__half2*>(&u);
    return __half22float2(h);
}
__device__ __forceinline__ u32 f2h2(float a, float b) {
    __half2 h = __float22half2_rn(make_float2(a, b));
    return *reinterpret_cast<u32*>(&h);
}

// ---------------- small utils ----------------

__global__ void zero_ints(int* __restrict__ p, int n) {
    int i = blockIdx.x * blockDim.x + threadIdx.x;
    if (i < n) p[i] = 0;
}

// fp32 x -> fp16 h0 (4 floats/thread)
__global__ void f2h_kernel(const float4* __restrict__ x, uint2* __restrict__ o, int n) {
    int i = blockIdx.x * blockDim.x + threadIdx.x;
    if (i < n) {
        float4 v = x[i];
        o[i] = make_uint2(f2h2(v.x, v.y), f2h2(v.z, v.w));
    }
}

// ---------------- CSR build: bucketed counting sort ----------------

__global__ void bucket_hist(const int* __restrict__ dst, int* __restrict__ bcnt) {
    __shared__ int lh[NB];
    for (int i = threadIdx.x; i < NB; i += blockDim.x) lh[i] = 0;
    __syncthreads();
    int stride = gridDim.x * blockDim.x;
    for (int e = blockIdx.x * blockDim.x + threadIdx.x; e < N_EDGES; e += stride)
        atomicAdd(&lh[dst[e] >> 8], 1);
    __syncthreads();
    for (int i = threadIdx.x; i < NB; i += blockDim.x)
        if (lh[i]) atomicAdd(&bcnt[i], lh[i]);
}

// single block: exclusive scan bcnt -> bbase[0..NB], init bcursor, row_ptr[N]=E
__global__ void bucket_scan(const int* __restrict__ bcnt, int* __restrict__ bbase,
                            int* __restrict__ bcursor, int* __restrict__ row_ptr) {
    __shared__ int s[512];
    int t = threadIdx.x;
    int v = (t < NB) ? bcnt[t] : 0;
    s[t] = v;
    __syncthreads();
    for (int off = 1; off < 512; off <<= 1) {
        int u = (t >= off) ? s[t - off] : 0;
        __syncthreads();
        s[t] += u;
        __syncthreads();
    }
    if (t < NB) { int ex = s[t] - v; bbase[t] = ex; bcursor[t] = ex; }
    if (t == 0) { bbase[NB] = N_EDGES; row_ptr[N_NODES] = N_EDGES; }
}

// fused rank+hist: one LDS atomic pass assigns ranks AND builds the histogram
__global__ __launch_bounds__(1024)
void pass1_bucket(const int* __restrict__ src, const int* __restrict__ dst,
                  int* __restrict__ bcursor, unsigned* __restrict__ pairs) {
    __shared__ int lh[NB], lbase[NB];
    int t = threadIdx.x;
    int e0 = blockIdx.x * PASS1_EPB;
    int n = min(PASS1_EPB, N_EDGES - e0);
    for (int i = t; i < NB; i += 1024) lh[i] = 0;
    __syncthreads();
    int dd[8], rr[8];
#pragma unroll
    for (int k = 0; k < 8; ++k) {
        int idx = k * 1024 + t;
        if (idx < n) {
            int d = dst[e0 + idx];
            dd[k] = d;
            rr[k] = atomicAdd(&lh[d >> 8], 1);
        }
    }
    __syncthreads();
    for (int i = t; i < NB; i += 1024) {
        int c = lh[i];
        lbase[i] = c ? atomicAdd(&bcursor[i], c) : 0;
    }
    __syncthreads();
#pragma unroll
    for (int k = 0; k < 8; ++k) {
        int idx = k * 1024 + t;
        if (idx < n) {
            int d = dd[k];
            pairs[lbase[d >> 8] + rr[k]] = (unsigned)src[e0 + idx] | ((unsigned)(d & 255) << 17);
        }
    }
}

// one block per bucket: LDS counting sort -> row_ptr + coalesced col
__global__ __launch_bounds__(1024)
void pass2_sort(const unsigned* __restrict__ pairs, const int* __restrict__ bbase,
                int* __restrict__ row_ptr, int* __restrict__ col) {
    __shared__ int sdeg[256], ssc[256];
    __shared__ int colst[CAP];
    int t = threadIdx.x;
    int b = blockIdx.x;
    int base = bbase[b];
    int cnt = bbase[b + 1] - base;
    int node0 = b << 8;
    int nn = min(256, N_NODES - node0);
    if (t < 256) sdeg[t] = 0;
    __syncthreads();
    unsigned vv[12];
    int rr[12];
#pragma unroll
    for (int k = 0; k < 12; ++k) {
        int j = k * 1024 + t;
        if (j < cnt) {
            unsigned v = pairs[base + j];
            vv[k] = v;
            rr[k] = atomicAdd(&sdeg[v >> 17], 1);
        }
    }
    __syncthreads();
    if (t < 256) ssc[t] = sdeg[t];
    __syncthreads();
    for (int off = 1; off < 256; off <<= 1) {
        int u = 0;
        if (t < 256 && t >= off) u = ssc[t - off];
        __syncthreads();
        if (t < 256) ssc[t] += u;
        __syncthreads();
    }
    if (t < 256) {
        int ex = ssc[t] - sdeg[t];
        ssc[t] = ex;                                   // exclusive base per node
        if (t < nn) row_ptr[node0 + t] = base + ex;
    }
    __syncthreads();
#pragma unroll
    for (int k = 0; k < 12; ++k) {
        int j = k * 1024 + t;
        if (j < cnt) {
            unsigned v = vv[k];
            int p = ssc[v >> 17] + rr[k];
            if (p < CAP) colst[p] = v & 0x1FFFF;
            else col[base + p] = v & 0x1FFFF;          // overflow path (never hit)
        }
    }
    __syncthreads();
    int lim = min(cnt, CAP);
    for (int j = t; j < lim; j += 1024) col[base + j] = colst[j];
}

// ---------------- fused SAGE layer (fp16 h) ----------------
// 64 nodes x 4 threads per block; each thread max-reduces full fp16 rows over
// 1/4 of the neighbors with v_pk_max_f16, then a 2-round shfl_xor butterfly.

template <int HOUT, bool RELU, bool LSM>
__global__ void sage_layer(const u32* __restrict__ h,       // fp16 rows: 8 u32/node
                           const int* __restrict__ row_ptr,
                           const int* __restrict__ col,
                           const float* __restrict__ Wl,
                           const float* __restrict__ Wr,
                           const float* __restrict__ b,
                           void* __restrict__ out) {
    __shared__ float sWl[HDIM * HOUT];
    __shared__ float sWr[HDIM * HOUT];
    __shared__ float sb[HOUT];
    int t = threadIdx.x;
    if (t < HDIM * HOUT) { sWl[t] = Wl[t]; sWr[t] = Wr[t]; }
    if (t < HOUT) sb[t] = b[t];
    __syncthreads();

    int nl = t >> 2, g = t & 3;
    int i = blockIdx.x * 64 + nl;
    if (i >= N_NODES) return;

    int beg = row_ptr[i], end = row_ptr[i + 1];
    const uint4* h4 = (const uint4*)h;   // 2 uint4 per node row

    u32 a0, a1, a2, a3, a4, a5, a6, a7;
    a0 = a1 = a2 = a3 = a4 = a5 = a6 = a7 = 0xFBFFFBFFu;  // packed -65504

    int j = beg + g;
    for (; j + 4 < end; j += 8) {
        int n0 = col[j], n1 = col[j + 4];
        uint4 p0 = h4[n0 * 2], p1 = h4[n0 * 2 + 1];
        uint4 q0 = h4[n1 * 2], q1 = h4[n1 * 2 + 1];
        a0 = pkmax(a0, pkmax(p0.x, q0.x));
        a1 = pkmax(a1, pkmax(p0.y, q0.y));
        a2 = pkmax(a2, pkmax(p0.z, q0.z));
        a3 = pkmax(a3, pkmax(p0.w, q0.w));
        a4 = pkmax(a4, pkmax(p1.x, q1.x));
        a5 = pkmax(a5, pkmax(p1.y, q1.y));
        a6 = pkmax(a6, pkmax(p1.z, q1.z));
        a7 = pkmax(a7, pkmax(p1.w, q1.w));
    }
    if (j < end) {
        int n0 = col[j];
        uint4 p0 = h4[n0 * 2], p1 = h4[n0 * 2 + 1];
        a0 = pkmax(a0, p0.x); a1 = pkmax(a1, p0.y);
        a2 = pkmax(a2, p0.z); a3 = pkmax(a3, p0.w);
        a4 = pkmax(a4, p1.x); a5 = pkmax(a5, p1.y);
        a6 = pkmax(a6, p1.z); a7 = pkmax(a7, p1.w);
    }
    // butterfly across the node's 4 lanes
#pragma unroll
    for (int m = 1; m <= 2; m <<= 1) {
        a0 = pkmax(a0, (u32)__shfl_xor((int)a0, m));
        a1 = pkmax(a1, (u32)__shfl_xor((int)a1, m));
        a2 = pkmax(a2, (u32)__shfl_xor((int)a2, m));
        a3 = pkmax(a3, (u32)__shfl_xor((int)a3, m));
        a4 = pkmax(a4, (u32)__shfl_xor((int)a4, m));
        a5 = pkmax(a5, (u32)__shfl_xor((int)a5, m));
        a6 = pkmax(a6, (u32)__shfl_xor((int)a6, m));
        a7 = pkmax(a7, (u32)__shfl_xor((int)a7, m));
    }
    if (beg == end) { a0 = a1 = a2 = a3 = a4 = a5 = a6 = a7 = 0u; }  // isolated -> 0

    float av[16], xv[16];
    {
        float2 f;
        f = h2f2(a0); av[0] = f.x; av[1] = f.y;
        f = h2f2(a1); av[2] = f.x; av[3] = f.y;
        f = h2f2(a2); av[4] = f.x; av[5] = f.y;
        f = h2f2(a3); av[6] = f.x; av[7] = f.y;
        f = h2f2(a4); av[8] = f.x; av[9] = f.y;
        f = h2f2(a5); av[10] = f.x; av[11] = f.y;
        f = h2f2(a6); av[12] = f.x; av[13] = f.y;
        f = h2f2(a7); av[14] = f.x; av[15] = f.y;
        uint4 x0 = h4[i * 2], x1 = h4[i * 2 + 1];
        f = h2f2(x0.x); xv[0] = f.x; xv[1] = f.y;
        f = h2f2(x0.y); xv[2] = f.x; xv[3] = f.y;
        f = h2f2(x0.z); xv[4] = f.x; xv[5] = f.y;
        f = h2f2(x0.w); xv[6] = f.x; xv[7] = f.y;
        f = h2f2(x1.x); xv[8] = f.x; xv[9] = f.y;
        f = h2f2(x1.y); xv[10] = f.x; xv[11] = f.y;
        f = h2f2(x1.z); xv[12] = f.x; xv[13] = f.y;
        f = h2f2(x1.w); xv[14] = f.x; xv[15] = f.y;
    }

    if (HOUT == 16) {
        float o[4];
#pragma unroll
        for (int c = 0; c < 4; ++c) o[c] = sb[g * 4 + c];
#pragma unroll
        for (int f = 0; f < 16; ++f) {
#pragma unroll
            for (int c = 0; c < 4; ++c)
                o[c] += av[f] * sWl[f * 16 + g * 4 + c] + xv[f] * sWr[f * 16 + g * 4 + c];
        }
        if (RELU) {
#pragma unroll
            for (int c = 0; c < 4; ++c) o[c] = fmaxf(o[c], 0.f);
        }
        ((uint2*)out)[i * 4 + g] = make_uint2(f2h2(o[0], o[1]), f2h2(o[2], o[3]));
    } else {  // HOUT == 2 final layer, fp32 out + log_softmax
        if (g == 0) {
            float o0 = sb[0], o1 = sb[1];
#pragma unroll
            for (int f = 0; f < 16; ++f) {
                o0 += av[f] * sWl[f * 2 + 0] + xv[f] * sWr[f * 2 + 0];
                o1 += av[f] * sWl[f * 2 + 1] + xv[f] * sWr[f * 2 + 1];
            }
            if (LSM) {
                float m = fmaxf(o0, o1);
                float lse = m + logf(expf(o0 - m) + expf(o1 - m));
                o0 -= lse;
                o1 -= lse;
            }
            ((float2*)out)[i] = make_float2(o0, o1);
        }
    }
}

// ---------------- launch ----------------

extern "C" void kernel_launch(void* const* d_in, const int* in_sizes, int n_in,
                              void* d_out, int out_size, void* d_ws, size_t ws_size,
                              hipStream_t stream) {
    const float* x      = (const float*)d_in[0];
    const int*   ei     = (const int*)d_in[1];
    const float* Wl1    = (const float*)d_in[2];
    const float* Wr1    = (const float*)d_in[3];
    const float* b1     = (const float*)d_in[4];
    const float* Wl_mid = (const float*)d_in[5];
    const float* Wr_mid = (const float*)d_in[6];
    const float* b_mid  = (const float*)d_in[7];
    const float* Wl7    = (const float*)d_in[8];
    const float* Wr7    = (const float*)d_in[9];
    const float* b7     = (const float*)d_in[10];
    float* out = (float*)d_out;

    const int* src = ei;
    const int* dst = ei + N_EDGES;

    char* ws = (char*)d_ws;
    size_t off = 0;
    auto alloc = [&](size_t bytes) {
        void* p = ws + off;
        off += (bytes + 255) & ~(size_t)255;
        return p;
    };
    unsigned* pairs  = (unsigned*)alloc((size_t)N_EDGES * 4);
    int*     col     = (int*)alloc((size_t)N_EDGES * 4);
    int*     row_ptr = (int*)alloc((size_t)(N_NODES + 1) * 4);
    int*     bcnt    = (int*)alloc((size_t)NB * 4);
    int*     bbase   = (int*)alloc((size_t)(NB + 1) * 4);
    int*     bcursor = (int*)alloc((size_t)NB * 4);
    u32*     h0      = (u32*)alloc((size_t)N_NODES * HDIM * 2);   // fp16
    u32*     hA      = (u32*)alloc((size_t)N_NODES * HDIM * 2);
    u32*     hB      = (u32*)alloc((size_t)N_NODES * HDIM * 2);

    dim3 bL((N_NODES + 63) / 64);

    // ---- CSR build + fp16 conversion ----
    zero_ints<<<(NB + 255) / 256, 256, 0, stream>>>(bcnt, NB);
    bucket_hist<<<512, 256, 0, stream>>>(dst, bcnt);
    f2h_kernel<<<(N_NODES * HDIM / 4 + 255) / 256, 256, 0, stream>>>(
        (const float4*)x, (uint2*)h0, N_NODES * HDIM / 4);
    bucket_scan<<<1, 512, 0, stream>>>(bcnt, bbase, bcursor, row_ptr);
    pass1_bucket<<<PASS1_BLOCKS, 1024, 0, stream>>>(src, dst, bcursor, pairs);
    pass2_sort<<<NB, 1024, 0, stream>>>(pairs, bbase, row_ptr, col);

    // ---- 7 fused layers ----
    sage_layer<16, true, false><<<bL, 256, 0, stream>>>(h0, row_ptr, col, Wl1, Wr1, b1, hA);

    u32* cur = hA;
    u32* nxt = hB;
    for (int i = 0; i < 5; ++i) {
        sage_layer<16, true, false><<<bL, 256, 0, stream>>>(
            cur, row_ptr, col, Wl_mid + i * 256, Wr_mid + i * 256, b_mid + i * 16, nxt);
        u32* tmp = cur; cur = nxt; nxt = tmp;
    }

    sage_layer<2, false, true><<<bL, 256, 0, stream>>>(cur, row_ptr, col, Wl7, Wr7, b7, out);
}